// Round 1
// baseline (8364.491 us; speedup 1.0000x reference)
//
#include <hip/hip_runtime.h>
#include <cmath>

// Problem constants (fixed by the reference)
#define B_  32
#define S_  196
#define D_  768
#define H_  12
#define E_  8
#define F_  3072
#define DH_ 64
#define T_  (B_ * S_)   // 6272 tokens; 6272 % 128 == 0

// ---------------------------------------------------------------------------
// Tiled fp32 GEMM: C[M,N] = A[M,K] @ B[K,N] (+bias, epilogue variants)
// BM=BN=128, BK=16, 256 threads, 8x8 micro-tile per thread.
// EPI: 0 = bias only, 1 = bias+exact GELU, 2 = moe accumulate:
//      C[r,c] += gates[r*E+expert] * (acc + bias[c])
// All M,N,K used here are multiples of 128/128/16 -> no bounds checks.
// ---------------------------------------------------------------------------
template<int EPI>
__global__ __launch_bounds__(256)
void gemm128(const float* __restrict__ A, const float* __restrict__ Bw,
             const float* __restrict__ bias, float* __restrict__ C,
             int M, int N, int K,
             const float* __restrict__ gates, int expert)
{
    constexpr int BK = 16;
    __shared__ float As[BK][132];   // [k][m], pad 132 to dodge store conflicts
    __shared__ float Bs[BK][128];   // [k][n]

    const int tid = threadIdx.x;
    const int tx  = tid & 15;       // N direction
    const int ty  = tid >> 4;       // M direction
    const int brow = blockIdx.y * 128;
    const int bcol = blockIdx.x * 128;

    // A-tile load mapping: 128 rows x 16 k, 2 float4 per thread
    const int rA = tid >> 2;            // 0..63
    const int cA = (tid & 3) << 2;      // 0,4,8,12
    // B-tile load mapping: 16 k x 128 cols, 2 float4 per thread
    const int rB = tid >> 5;            // 0..7
    const int cB = (tid & 31) << 2;     // 0..124

    const float* Aptr = A + (size_t)(brow + rA) * K + cA;
    const float* Bptr = Bw + (size_t)rB * N + bcol + cB;

    float acc[8][8];
    #pragma unroll
    for (int i = 0; i < 8; ++i)
        #pragma unroll
        for (int j = 0; j < 8; ++j) acc[i][j] = 0.f;

    for (int k0 = 0; k0 < K; k0 += BK) {
        float4 a0 = *(const float4*)(Aptr);
        float4 a1 = *(const float4*)(Aptr + (size_t)64 * K);
        float4 b0 = *(const float4*)(Bptr);
        float4 b1 = *(const float4*)(Bptr + (size_t)8 * N);
        Aptr += BK;
        Bptr += (size_t)BK * N;

        __syncthreads();   // previous iter's compute done before overwrite
        As[cA+0][rA]    = a0.x; As[cA+1][rA]    = a0.y;
        As[cA+2][rA]    = a0.z; As[cA+3][rA]    = a0.w;
        As[cA+0][rA+64] = a1.x; As[cA+1][rA+64] = a1.y;
        As[cA+2][rA+64] = a1.z; As[cA+3][rA+64] = a1.w;
        *(float4*)&Bs[rB][cB]     = b0;
        *(float4*)&Bs[rB + 8][cB] = b1;
        __syncthreads();

        #pragma unroll
        for (int kk = 0; kk < BK; ++kk) {
            float4 af0 = *(const float4*)&As[kk][ty * 8];
            float4 af1 = *(const float4*)&As[kk][ty * 8 + 4];
            float4 bf0 = *(const float4*)&Bs[kk][tx * 8];
            float4 bf1 = *(const float4*)&Bs[kk][tx * 8 + 4];
            float av[8] = {af0.x, af0.y, af0.z, af0.w, af1.x, af1.y, af1.z, af1.w};
            float bv[8] = {bf0.x, bf0.y, bf0.z, bf0.w, bf1.x, bf1.y, bf1.z, bf1.w};
            #pragma unroll
            for (int i = 0; i < 8; ++i)
                #pragma unroll
                for (int j = 0; j < 8; ++j)
                    acc[i][j] = fmaf(av[i], bv[j], acc[i][j]);
        }
    }

    #pragma unroll
    for (int i = 0; i < 8; ++i) {
        const int r = brow + ty * 8 + i;
        float g = 0.f;
        if (EPI == 2) g = gates[(size_t)r * E_ + expert];
        #pragma unroll
        for (int j = 0; j < 8; ++j) {
            const int c = bcol + tx * 8 + j;
            float vv = acc[i][j] + bias[c];
            if (EPI == 1) vv = 0.5f * vv * (1.0f + erff(vv * 0.70710678118654752f));
            const size_t idx = (size_t)r * N + c;
            if (EPI == 2) C[idx] += g * vv;
            else          C[idx] = vv;
        }
    }
}

// ---------------------------------------------------------------------------
// Attention: one block per (b,h). K-tile in LDS; per-thread q-row; scores
// staged (transposed: sc[k*S+t]) in global scratch for coalesced access.
// ---------------------------------------------------------------------------
__global__ __launch_bounds__(256)
void attn_kernel(const float* __restrict__ qh, const float* __restrict__ kh,
                 const float* __restrict__ vh, float* __restrict__ ctx,
                 float* __restrict__ scratch)
{
    __shared__ float Ks[S_ * DH_];   // 50,176 B
    const int bh = blockIdx.x;
    const int b  = bh / H_;
    const int h  = bh % H_;
    const int tid = threadIdx.x;

    for (int idx = tid; idx < S_ * DH_; idx += 256) {
        const int s = idx >> 6, d = idx & 63;
        Ks[idx] = kh[((size_t)(b * S_ + s)) * D_ + h * DH_ + d];
    }
    __syncthreads();
    if (tid >= S_) return;

    float qf[DH_];
    const float* qrow = qh + ((size_t)(b * S_ + tid)) * D_ + h * DH_;
    #pragma unroll
    for (int d4 = 0; d4 < 16; ++d4) {
        float4 v4 = *(const float4*)(qrow + d4 * 4);
        qf[d4*4+0] = v4.x; qf[d4*4+1] = v4.y; qf[d4*4+2] = v4.z; qf[d4*4+3] = v4.w;
    }

    float* sc = scratch + (size_t)bh * (S_ * S_) + tid;   // stride S_ per key
    float m = -1e30f;
    for (int k = 0; k < S_; ++k) {
        const float* kr = &Ks[k * DH_];
        float s0 = 0.f, s1 = 0.f, s2 = 0.f, s3 = 0.f;
        #pragma unroll
        for (int d = 0; d < DH_; d += 4) {
            s0 = fmaf(qf[d+0], kr[d+0], s0);
            s1 = fmaf(qf[d+1], kr[d+1], s1);
            s2 = fmaf(qf[d+2], kr[d+2], s2);
            s3 = fmaf(qf[d+3], kr[d+3], s3);
        }
        const float sv = (s0 + s1 + s2 + s3) * 0.125f;   // 1/sqrt(64)
        sc[(size_t)k * S_] = sv;
        m = fmaxf(m, sv);
    }
    float l = 0.f;
    for (int k = 0; k < S_; ++k) {
        const float p = expf(sc[(size_t)k * S_] - m);
        sc[(size_t)k * S_] = p;
        l += p;
    }
    float acc[DH_];
    #pragma unroll
    for (int d = 0; d < DH_; ++d) acc[d] = 0.f;
    const float* vbase = vh + ((size_t)b * S_) * D_ + h * DH_;
    for (int k = 0; k < S_; ++k) {
        const float p = sc[(size_t)k * S_];
        const float* vr = vbase + (size_t)k * D_;
        #pragma unroll
        for (int d4 = 0; d4 < 16; ++d4) {
            float4 v4 = *(const float4*)(vr + d4 * 4);
            acc[d4*4+0] = fmaf(p, v4.x, acc[d4*4+0]);
            acc[d4*4+1] = fmaf(p, v4.y, acc[d4*4+1]);
            acc[d4*4+2] = fmaf(p, v4.z, acc[d4*4+2]);
            acc[d4*4+3] = fmaf(p, v4.w, acc[d4*4+3]);
        }
    }
    const float inv = 1.f / l;
    float* crow = ctx + ((size_t)(b * S_ + tid)) * D_ + h * DH_;
    #pragma unroll
    for (int d = 0; d < DH_; ++d) crow[d] = acc[d] * inv;
}

// ---------------------------------------------------------------------------
// Residual + LayerNorm: out = LN(a + b) * g + beta. One block per token.
// ---------------------------------------------------------------------------
__device__ __forceinline__ float block_sum(float v, float* red)
{
    __syncthreads();   // protect red[] reuse across calls
    const int lane = threadIdx.x & 63;
    const int wid  = threadIdx.x >> 6;
    #pragma unroll
    for (int off = 32; off > 0; off >>= 1) v += __shfl_down(v, off);
    if (lane == 0) red[wid] = v;
    __syncthreads();
    return red[0] + red[1] + red[2] + red[3];
}

__global__ __launch_bounds__(256)
void ln_kernel(const float* __restrict__ a, const float* __restrict__ bres,
               const float* __restrict__ g, const float* __restrict__ beta,
               float* __restrict__ out)
{
    __shared__ float red[4];
    const int t   = blockIdx.x;
    const int tid = threadIdx.x;
    const float* ar = a    + (size_t)t * D_;
    const float* br = bres + (size_t)t * D_;

    float vals[3];
    float s = 0.f;
    #pragma unroll
    for (int i = 0; i < 3; ++i) {
        const int d = tid + i * 256;
        const float x = ar[d] + br[d];
        vals[i] = x;
        s += x;
    }
    s = block_sum(s, red);
    const float mu = s * (1.f / D_);
    float qv = 0.f;
    #pragma unroll
    for (int i = 0; i < 3; ++i) { const float dv = vals[i] - mu; qv += dv * dv; }
    qv = block_sum(qv, red);
    const float rstd = rsqrtf(qv * (1.f / D_) + 1e-5f);
    #pragma unroll
    for (int i = 0; i < 3; ++i) {
        const int d = tid + i * 256;
        out[(size_t)t * D_ + d] = (vals[i] - mu) * rstd * g[d] + beta[d];
    }
}

// ---------------------------------------------------------------------------
// Gate: gates = softmax(x @ Wg + bg). One wave per token, 4 tokens/block.
// ---------------------------------------------------------------------------
__global__ __launch_bounds__(256)
void gate_kernel(const float* __restrict__ x, const float* __restrict__ Wg,
                 const float* __restrict__ bg, float* __restrict__ gates)
{
    const int lane = threadIdx.x & 63;
    const int wid  = threadIdx.x >> 6;
    const int t = blockIdx.x * 4 + wid;
    const float* xr = x + (size_t)t * D_;

    float accv[E_];
    #pragma unroll
    for (int e = 0; e < E_; ++e) accv[e] = 0.f;
    for (int d = lane; d < D_; d += 64) {
        const float xv = xr[d];
        const float* wr = Wg + (size_t)d * E_;
        #pragma unroll
        for (int e = 0; e < E_; ++e) accv[e] = fmaf(xv, wr[e], accv[e]);
    }
    #pragma unroll
    for (int e = 0; e < E_; ++e) {
        #pragma unroll
        for (int off = 32; off > 0; off >>= 1)
            accv[e] += __shfl_down(accv[e], off);
    }
    if (lane == 0) {
        float mx = -1e30f;
        #pragma unroll
        for (int e = 0; e < E_; ++e) { accv[e] += bg[e]; mx = fmaxf(mx, accv[e]); }
        float l = 0.f;
        #pragma unroll
        for (int e = 0; e < E_; ++e) { const float p = expf(accv[e] - mx); accv[e] = p; l += p; }
        const float inv = 1.f / l;
        #pragma unroll
        for (int e = 0; e < E_; ++e) gates[(size_t)t * E_ + e] = accv[e] * inv;
    }
}

__global__ void zero_kernel(float* __restrict__ p, int n)
{
    const int i = blockIdx.x * blockDim.x + threadIdx.x;
    if (i < n) p[i] = 0.f;
}

// ---------------------------------------------------------------------------
// Orchestration.  Workspace layout (floats), total ~165.4 MiB:
//   [0,TD)      qh        -> later reused as attn_out
//   [TD,2TD)    kh        -> later reused as x (LN1 out)
//   [2TD,3TD)   vh        -> later reused as gates (T*E)
//   [3TD,4TD)   ctx
//   [4TD,5TD)   moe accumulator
//   [5TD,5TD+TF) h buffer (T*F) ; also attn scores (B*H*S*S <= T*F) earlier
// ---------------------------------------------------------------------------
extern "C" void kernel_launch(void* const* d_in, const int* in_sizes, int n_in,
                              void* d_out, int out_size, void* d_ws, size_t ws_size,
                              hipStream_t stream)
{
    const float* q    = (const float*)d_in[0];
    const float* k    = (const float*)d_in[1];
    const float* v    = (const float*)d_in[2];
    const float* Wq   = (const float*)d_in[3];
    const float* bq   = (const float*)d_in[4];
    const float* Wk   = (const float*)d_in[5];
    const float* bk   = (const float*)d_in[6];
    const float* Wv   = (const float*)d_in[7];
    const float* bv   = (const float*)d_in[8];
    const float* Wo   = (const float*)d_in[9];
    const float* bo   = (const float*)d_in[10];
    const float* ln1g = (const float*)d_in[11];
    const float* ln1b = (const float*)d_in[12];
    const float* ln2g = (const float*)d_in[13];
    const float* ln2b = (const float*)d_in[14];
    const float* Wg   = (const float*)d_in[15];
    const float* bg   = (const float*)d_in[16];
    const float* W1   = (const float*)d_in[17];
    const float* b1   = (const float*)d_in[18];
    const float* W2   = (const float*)d_in[19];
    const float* b2   = (const float*)d_in[20];
    float* out = (float*)d_out;
    float* ws  = (float*)d_ws;

    const size_t TD = (size_t)T_ * D_;
    float* qh      = ws;
    float* khb     = ws + TD;
    float* vhb     = ws + 2 * TD;
    float* ctx     = ws + 3 * TD;
    float* moe     = ws + 4 * TD;
    float* big     = ws + 5 * TD;   // h buffer / attention scores
    float* attnout = qh;            // reuse (qh dead after attention)
    float* x       = khb;           // reuse (kh dead after attention)
    float* gates   = vhb;           // reuse (vh dead after attention)

    const dim3 blk(256);
    const dim3 gD(D_ / 128, T_ / 128);   // (6, 49)
    const dim3 gF(F_ / 128, T_ / 128);   // (24, 49)

    // QKV projections
    gemm128<0><<<gD, blk, 0, stream>>>(q, Wq, bq, qh,  T_, D_, D_, nullptr, 0);
    gemm128<0><<<gD, blk, 0, stream>>>(k, Wk, bk, khb, T_, D_, D_, nullptr, 0);
    gemm128<0><<<gD, blk, 0, stream>>>(v, Wv, bv, vhb, T_, D_, D_, nullptr, 0);

    // Attention
    attn_kernel<<<dim3(B_ * H_), blk, 0, stream>>>(qh, khb, vhb, ctx, big);

    // Output projection, residual + LN1
    gemm128<0><<<gD, blk, 0, stream>>>(ctx, Wo, bo, attnout, T_, D_, D_, nullptr, 0);
    ln_kernel<<<dim3(T_), blk, 0, stream>>>(q, attnout, ln1g, ln1b, x);

    // MoE gating
    gate_kernel<<<dim3(T_ / 4), blk, 0, stream>>>(x, Wg, bg, gates);

    // MoE experts (sequential; h buffer reused)
    const int nmoe = T_ * D_;
    zero_kernel<<<dim3((nmoe + 255) / 256), blk, 0, stream>>>(moe, nmoe);
    for (int e = 0; e < E_; ++e) {
        gemm128<1><<<gF, blk, 0, stream>>>(x, W1 + (size_t)e * D_ * F_,
                                           b1 + (size_t)e * F_, big,
                                           T_, F_, D_, nullptr, 0);
        gemm128<2><<<gD, blk, 0, stream>>>(big, W2 + (size_t)e * F_ * D_,
                                           b2 + (size_t)e * D_, moe,
                                           T_, D_, F_, gates, e);
    }

    // Residual + LN2 -> output
    ln_kernel<<<dim3(T_), blk, 0, stream>>>(x, moe, ln2g, ln2b, out);
}

// Round 2
// 1710.985 us; speedup vs baseline: 4.8887x; 4.8887x over previous
//
#include <hip/hip_runtime.h>
#include <cmath>

// Problem constants (fixed by the reference)
#define B_  32
#define S_  196
#define D_  768
#define H_  12
#define E_  8
#define F_  3072
#define DH_ 64
#define T_  (B_ * S_)   // 6272 tokens; 6272 % 128 == 0

typedef unsigned short ushort_t;
typedef short   s16x8   __attribute__((ext_vector_type(8)));
typedef __bf16  bf16x8_t __attribute__((ext_vector_type(8)));
typedef float   f32x4   __attribute__((ext_vector_type(4)));

// 16-byte MFMA A/B fragment. Converts to whichever vector type the
// gfx950 mfma builtin's prototype wants (short8 vs v8bf16 differ across
// ROCm versions) — only one user-defined conversion is viable per build.
struct ABFrag {
    unsigned int r[4];
    __device__ operator s16x8()    const { return __builtin_bit_cast(s16x8, *this); }
    __device__ operator bf16x8_t() const { return __builtin_bit_cast(bf16x8_t, *this); }
};

__device__ __forceinline__ ushort_t f2bf(float f) {
    unsigned int x = __float_as_uint(f);
    return (ushort_t)((x + 0x7fffu + ((x >> 16) & 1u)) >> 16);   // RNE
}

// async global->LDS, 16B per lane. LDS dest must be wave-uniform base
// (HW adds lane*16); global src is per-lane.
__device__ __forceinline__ void glds16(const void* g, void* l) {
    __builtin_amdgcn_global_load_lds((const __attribute__((address_space(1))) void*)g,
                                     (__attribute__((address_space(3))) void*)l,
                                     16, 0, 0);
}

// ---------------------------------------------------------------------------
// bf16 MFMA GEMM (m97 structure): C[M,N] = A[M,K] @ Bt[N,K]^T
// A row-major bf16, Bt row-major bf16 (i.e. B transposed). 128x128 tile,
// BK=32, 256 threads (4 waves, 2x2), each wave 64x64 = 4x4 frags 16x16.
// EPI: 0 = fp32 out, +bias. 1 = bf16 out, +bias then exact GELU.
//      2 = fp32 accumulate: C += gates[row*E+expert] * (acc + bias).
// ---------------------------------------------------------------------------
template<int EPI>
__global__ __launch_bounds__(256)
void gemm_bt(const ushort_t* __restrict__ A, const ushort_t* __restrict__ Bt,
             const float* __restrict__ bias,
             float* __restrict__ Cf, ushort_t* __restrict__ Cb,
             int M, int N, int K,
             const float* __restrict__ gates, int expert)
{
    __shared__ ushort_t Alds[128 * 32];   // [row][k] linear, 8 KB
    __shared__ ushort_t Blds[128 * 32];   // [col][k] linear, 8 KB

    const int tid = threadIdx.x;
    const int w  = tid >> 6, l = tid & 63;
    const int wr = w >> 1,  wc = w & 1;     // wave 2x2 grid
    const int rg = l >> 4,  fr = l & 15;    // k-group / row-col within frag
    const int brow = blockIdx.y * 128;
    const int bcol = blockIdx.x * 128;

    // staging: thread t handles 8 contiguous bf16 at tile elem t*8 (+2048)
    const int srow = tid >> 2;            // 0..63
    const int scol = (tid & 3) << 3;      // 0,8,16,24
    const ushort_t* gA = A  + (size_t)(brow + srow) * K + scol;
    const ushort_t* gB = Bt + (size_t)(bcol + srow) * K + scol;
    ushort_t* lA = &Alds[w * 512];        // wave-uniform LDS dest
    ushort_t* lB = &Blds[w * 512];

    f32x4 acc[4][4] = {};

    const int aoff = (wr * 64 + fr) * 32 + rg * 8;
    const int boff = (wc * 64 + fr) * 32 + rg * 8;

    for (int k0 = 0; k0 < K; k0 += 32) {
        if (k0) __syncthreads();          // prev compute done before overwrite
        glds16(gA,                  lA);
        glds16(gA + (size_t)64 * K, lA + 2048);
        glds16(gB,                  lB);
        glds16(gB + (size_t)64 * K, lB + 2048);
        gA += 32; gB += 32;
        __syncthreads();                  // drains vmcnt before barrier

        ABFrag af[4], bf[4];
        #pragma unroll
        for (int m = 0; m < 4; ++m) af[m] = *(const ABFrag*)&Alds[aoff + m * 512];
        #pragma unroll
        for (int n = 0; n < 4; ++n) bf[n] = *(const ABFrag*)&Blds[boff + n * 512];
        #pragma unroll
        for (int m = 0; m < 4; ++m)
            #pragma unroll
            for (int n = 0; n < 4; ++n)
                acc[m][n] = __builtin_amdgcn_mfma_f32_16x16x32_bf16(
                                af[m], bf[n], acc[m][n], 0, 0, 0);
    }

    // epilogue: D col = lane&15, row = (lane>>4)*4 + reg (m89-verified)
    #pragma unroll
    for (int m = 0; m < 4; ++m) {
        #pragma unroll
        for (int n = 0; n < 4; ++n) {
            const int col = bcol + wc * 64 + n * 16 + fr;
            const float bv = bias[col];
            #pragma unroll
            for (int j = 0; j < 4; ++j) {
                const int row = brow + wr * 64 + m * 16 + rg * 4 + j;
                float vv = acc[m][n][j] + bv;
                if (EPI == 0) {
                    Cf[(size_t)row * N + col] = vv;
                } else if (EPI == 1) {
                    vv = 0.5f * vv * (1.0f + erff(vv * 0.70710678118654752f));
                    Cb[(size_t)row * N + col] = f2bf(vv);
                } else {
                    Cf[(size_t)row * N + col] +=
                        gates[(size_t)row * E_ + expert] * vv;
                }
            }
        }
    }
}

// ---------------------------------------------------------------------------
// fp32 -> bf16 linear convert (4 elems/thread, exact grid)
// ---------------------------------------------------------------------------
__global__ __launch_bounds__(256)
void convert_bf16(const float* __restrict__ in, ushort_t* __restrict__ out)
{
    const int i = blockIdx.x * 256 + threadIdx.x;
    float4 v = ((const float4*)in)[i];
    ushort4 o;
    o.x = f2bf(v.x); o.y = f2bf(v.y); o.z = f2bf(v.z); o.w = f2bf(v.w);
    ((ushort4*)out)[i] = o;
}

// ---------------------------------------------------------------------------
// fp32 [R][C] -> bf16 [C][R] tile transpose (weights -> B^T layout)
// R, C multiples of 64.
// ---------------------------------------------------------------------------
__global__ __launch_bounds__(256)
void transpose_to_bf16(const float* __restrict__ in, ushort_t* __restrict__ out,
                       int R, int C)
{
    __shared__ float tile[64][65];
    const int bc = blockIdx.x * 64;           // col tile in 'in'
    const int br = blockIdx.y * 64;           // row tile in 'in'
    const int lr = threadIdx.x >> 4;          // 0..15
    const int lc = (threadIdx.x & 15) << 2;   // 0..60
    #pragma unroll
    for (int i = 0; i < 64; i += 16) {
        float4 v = *(const float4*)&in[(size_t)(br + lr + i) * C + bc + lc];
        tile[lr + i][lc + 0] = v.x; tile[lr + i][lc + 1] = v.y;
        tile[lr + i][lc + 2] = v.z; tile[lr + i][lc + 3] = v.w;
    }
    __syncthreads();
    #pragma unroll
    for (int i = 0; i < 64; i += 16) {
        const int orow = lr + i;              // row in out (= col in in)
        ushort4 o;
        o.x = f2bf(tile[lc + 0][orow]);
        o.y = f2bf(tile[lc + 1][orow]);
        o.z = f2bf(tile[lc + 2][orow]);
        o.w = f2bf(tile[lc + 3][orow]);
        *(ushort4*)&out[(size_t)(bc + orow) * R + br + lc] = o;
    }
}

// ---------------------------------------------------------------------------
// Attention: one block per (b,h). K-tile in LDS; per-thread q-row; scores
// staged (transposed: sc[k*S+t]) in global scratch for coalesced access.
// ---------------------------------------------------------------------------
__global__ __launch_bounds__(256)
void attn_kernel(const float* __restrict__ qh, const float* __restrict__ kh,
                 const float* __restrict__ vh, float* __restrict__ ctx,
                 float* __restrict__ scratch)
{
    __shared__ float Ks[S_ * DH_];   // 50,176 B
    const int bh = blockIdx.x;
    const int b  = bh / H_;
    const int h  = bh % H_;
    const int tid = threadIdx.x;

    for (int idx = tid; idx < S_ * DH_; idx += 256) {
        const int s = idx >> 6, d = idx & 63;
        Ks[idx] = kh[((size_t)(b * S_ + s)) * D_ + h * DH_ + d];
    }
    __syncthreads();
    if (tid >= S_) return;

    float qf[DH_];
    const float* qrow = qh + ((size_t)(b * S_ + tid)) * D_ + h * DH_;
    #pragma unroll
    for (int d4 = 0; d4 < 16; ++d4) {
        float4 v4 = *(const float4*)(qrow + d4 * 4);
        qf[d4*4+0] = v4.x; qf[d4*4+1] = v4.y; qf[d4*4+2] = v4.z; qf[d4*4+3] = v4.w;
    }

    float* sc = scratch + (size_t)bh * (S_ * S_) + tid;   // stride S_ per key
    float m = -1e30f;
    for (int k = 0; k < S_; ++k) {
        const float* kr = &Ks[k * DH_];
        float s0 = 0.f, s1 = 0.f, s2 = 0.f, s3 = 0.f;
        #pragma unroll
        for (int d = 0; d < DH_; d += 4) {
            s0 = fmaf(qf[d+0], kr[d+0], s0);
            s1 = fmaf(qf[d+1], kr[d+1], s1);
            s2 = fmaf(qf[d+2], kr[d+2], s2);
            s3 = fmaf(qf[d+3], kr[d+3], s3);
        }
        const float sv = (s0 + s1 + s2 + s3) * 0.125f;   // 1/sqrt(64)
        sc[(size_t)k * S_] = sv;
        m = fmaxf(m, sv);
    }
    float l = 0.f;
    for (int k = 0; k < S_; ++k) {
        const float p = expf(sc[(size_t)k * S_] - m);
        sc[(size_t)k * S_] = p;
        l += p;
    }
    float acc[DH_];
    #pragma unroll
    for (int d = 0; d < DH_; ++d) acc[d] = 0.f;
    const float* vbase = vh + ((size_t)b * S_) * D_ + h * DH_;
    for (int k = 0; k < S_; ++k) {
        const float p = sc[(size_t)k * S_];
        const float* vr = vbase + (size_t)k * D_;
        #pragma unroll
        for (int d4 = 0; d4 < 16; ++d4) {
            float4 v4 = *(const float4*)(vr + d4 * 4);
            acc[d4*4+0] = fmaf(p, v4.x, acc[d4*4+0]);
            acc[d4*4+1] = fmaf(p, v4.y, acc[d4*4+1]);
            acc[d4*4+2] = fmaf(p, v4.z, acc[d4*4+2]);
            acc[d4*4+3] = fmaf(p, v4.w, acc[d4*4+3]);
        }
    }
    const float inv = 1.f / l;
    float* crow = ctx + ((size_t)(b * S_ + tid)) * D_ + h * DH_;
    #pragma unroll
    for (int d = 0; d < DH_; ++d) crow[d] = acc[d] * inv;
}

// ---------------------------------------------------------------------------
// Residual + LayerNorm: out = LN(a + b) * g + beta. One block per token.
// ---------------------------------------------------------------------------
__device__ __forceinline__ float block_sum(float v, float* red)
{
    __syncthreads();
    const int lane = threadIdx.x & 63;
    const int wid  = threadIdx.x >> 6;
    #pragma unroll
    for (int off = 32; off > 0; off >>= 1) v += __shfl_down(v, off);
    if (lane == 0) red[wid] = v;
    __syncthreads();
    return red[0] + red[1] + red[2] + red[3];
}

__global__ __launch_bounds__(256)
void ln_kernel(const float* __restrict__ a, const float* __restrict__ bres,
               const float* __restrict__ g, const float* __restrict__ beta,
               float* __restrict__ out)
{
    __shared__ float red[4];
    const int t   = blockIdx.x;
    const int tid = threadIdx.x;
    const float* ar = a    + (size_t)t * D_;
    const float* br = bres + (size_t)t * D_;

    float vals[3];
    float s = 0.f;
    #pragma unroll
    for (int i = 0; i < 3; ++i) {
        const int d = tid + i * 256;
        const float x = ar[d] + br[d];
        vals[i] = x;
        s += x;
    }
    s = block_sum(s, red);
    const float mu = s * (1.f / D_);
    float qv = 0.f;
    #pragma unroll
    for (int i = 0; i < 3; ++i) { const float dv = vals[i] - mu; qv += dv * dv; }
    qv = block_sum(qv, red);
    const float rstd = rsqrtf(qv * (1.f / D_) + 1e-5f);
    #pragma unroll
    for (int i = 0; i < 3; ++i) {
        const int d = tid + i * 256;
        out[(size_t)t * D_ + d] = (vals[i] - mu) * rstd * g[d] + beta[d];
    }
}

// ---------------------------------------------------------------------------
// Gate: gates = softmax(x @ Wg + bg). One wave per token, 4 tokens/block.
// ---------------------------------------------------------------------------
__global__ __launch_bounds__(256)
void gate_kernel(const float* __restrict__ x, const float* __restrict__ Wg,
                 const float* __restrict__ bg, float* __restrict__ gates)
{
    const int lane = threadIdx.x & 63;
    const int wid  = threadIdx.x >> 6;
    const int t = blockIdx.x * 4 + wid;
    const float* xr = x + (size_t)t * D_;

    float accv[E_];
    #pragma unroll
    for (int e = 0; e < E_; ++e) accv[e] = 0.f;
    for (int d = lane; d < D_; d += 64) {
        const float xv = xr[d];
        const float* wr = Wg + (size_t)d * E_;
        #pragma unroll
        for (int e = 0; e < E_; ++e) accv[e] = fmaf(xv, wr[e], accv[e]);
    }
    #pragma unroll
    for (int e = 0; e < E_; ++e) {
        #pragma unroll
        for (int off = 32; off > 0; off >>= 1)
            accv[e] += __shfl_down(accv[e], off);
    }
    if (lane == 0) {
        float mx = -1e30f;
        #pragma unroll
        for (int e = 0; e < E_; ++e) { accv[e] += bg[e]; mx = fmaxf(mx, accv[e]); }
        float l = 0.f;
        #pragma unroll
        for (int e = 0; e < E_; ++e) { const float p = expf(accv[e] - mx); accv[e] = p; l += p; }
        const float inv = 1.f / l;
        #pragma unroll
        for (int e = 0; e < E_; ++e) gates[(size_t)t * E_ + e] = accv[e] * inv;
    }
}

__global__ void zero_kernel(float* __restrict__ p, int n)
{
    const int i = blockIdx.x * blockDim.x + threadIdx.x;
    if (i < n) p[i] = 0.f;
}

// ---------------------------------------------------------------------------
// Orchestration. Workspace layout (float offsets), total ~150.2 MB:
//   [0,TD)        qh   -> attnout after attention
//   [TD,2TD)      kh   -> x after attention
//   [2TD,3TD)     vh   -> xb (bf16) + gates after attention
//   [3TD,4TD)     ctx
//   [4TD,5TD)     moe  (also start of attn scores, dead before moe zeroed)
//   [5TD,7TD)     big bf16 region: qb/kb/vb -> ctxb -> hb [T*F bf16]
//                 (attn scores span [4TD, 4TD+B*H*S*S) over moe+big)
//   [4TD+SC, ...) Wqt..Wot, w1t, w2t (bf16, written outside scores lifetime)
// ---------------------------------------------------------------------------
extern "C" void kernel_launch(void* const* d_in, const int* in_sizes, int n_in,
                              void* d_out, int out_size, void* d_ws, size_t ws_size,
                              hipStream_t stream)
{
    const float* q    = (const float*)d_in[0];
    const float* k    = (const float*)d_in[1];
    const float* v    = (const float*)d_in[2];
    const float* Wq   = (const float*)d_in[3];
    const float* bq   = (const float*)d_in[4];
    const float* Wk   = (const float*)d_in[5];
    const float* bk   = (const float*)d_in[6];
    const float* Wv   = (const float*)d_in[7];
    const float* bv   = (const float*)d_in[8];
    const float* Wo   = (const float*)d_in[9];
    const float* bo   = (const float*)d_in[10];
    const float* ln1g = (const float*)d_in[11];
    const float* ln1b = (const float*)d_in[12];
    const float* ln2g = (const float*)d_in[13];
    const float* ln2b = (const float*)d_in[14];
    const float* Wg   = (const float*)d_in[15];
    const float* bg   = (const float*)d_in[16];
    const float* W1   = (const float*)d_in[17];
    const float* b1   = (const float*)d_in[18];
    const float* W2   = (const float*)d_in[19];
    const float* b2   = (const float*)d_in[20];
    float* out = (float*)d_out;
    float* ws  = (float*)d_ws;

    const size_t TD = (size_t)T_ * D_;                 // 4,816,896
    const size_t SC = (size_t)B_ * H_ * S_ * S_;       // 14,751,744

    float* qh     = ws;
    float* kh     = ws + TD;
    float* vh     = ws + 2 * TD;
    float* ctx    = ws + 3 * TD;
    float* moe    = ws + 4 * TD;
    float* scores = ws + 4 * TD;                       // overlaps moe+big
    ushort_t* bigu = (ushort_t*)(ws + 5 * TD);
    ushort_t* qb   = bigu;
    ushort_t* kb   = bigu + TD;
    ushort_t* vb   = bigu + 2 * TD;
    ushort_t* ctxb = bigu;                             // after scores dead
    ushort_t* hb   = bigu;                             // T*F bf16, phase 5
    ushort_t* xb   = (ushort_t*)vh;                    // vh dead post-attn
    float* gates   = vh + TD / 2;                      // after xb
    float* attnout = qh;
    float* x       = kh;

    ushort_t* wqt = (ushort_t*)(ws + 4 * TD + SC);     // past scores end
    ushort_t* wkt = wqt + (size_t)D_ * D_;
    ushort_t* wvt = wkt + (size_t)D_ * D_;
    ushort_t* wot = wvt + (size_t)D_ * D_;
    ushort_t* w1t = wot + (size_t)D_ * D_;             // F*D per expert
    ushort_t* w2t = w1t + (size_t)F_ * D_;             // D*F per expert

    const dim3 blk(256);
    const dim3 gD(D_ / 128, T_ / 128);   // (6, 49)
    const dim3 gF(F_ / 128, T_ / 128);   // (24, 49)
    const int cgrid = (int)(TD / 1024);  // exact: TD % 1024 == 0

    // Phase 1: convert inputs, transpose+convert projection weights, QKV GEMMs
    convert_bf16<<<cgrid, blk, 0, stream>>>(q, qb);
    convert_bf16<<<cgrid, blk, 0, stream>>>(k, kb);
    convert_bf16<<<cgrid, blk, 0, stream>>>(v, vb);
    transpose_to_bf16<<<dim3(D_/64, D_/64), blk, 0, stream>>>(Wq, wqt, D_, D_);
    transpose_to_bf16<<<dim3(D_/64, D_/64), blk, 0, stream>>>(Wk, wkt, D_, D_);
    transpose_to_bf16<<<dim3(D_/64, D_/64), blk, 0, stream>>>(Wv, wvt, D_, D_);
    transpose_to_bf16<<<dim3(D_/64, D_/64), blk, 0, stream>>>(Wo, wot, D_, D_);
    gemm_bt<0><<<gD, blk, 0, stream>>>(qb, wqt, bq, qh, nullptr, T_, D_, D_, nullptr, 0);
    gemm_bt<0><<<gD, blk, 0, stream>>>(kb, wkt, bk, kh, nullptr, T_, D_, D_, nullptr, 0);
    gemm_bt<0><<<gD, blk, 0, stream>>>(vb, wvt, bv, vh, nullptr, T_, D_, D_, nullptr, 0);

    // Phase 2: attention (scores scratch over moe+big region)
    attn_kernel<<<dim3(B_ * H_), blk, 0, stream>>>(qh, kh, vh, ctx, scores);

    // Phase 3: output projection, residual + LN1
    convert_bf16<<<cgrid, blk, 0, stream>>>(ctx, ctxb);
    gemm_bt<0><<<gD, blk, 0, stream>>>(ctxb, wot, bo, attnout, nullptr, T_, D_, D_, nullptr, 0);
    ln_kernel<<<dim3(T_), blk, 0, stream>>>(q, attnout, ln1g, ln1b, x);

    // Phase 4: gating + x -> bf16
    gate_kernel<<<dim3(T_ / 4), blk, 0, stream>>>(x, Wg, bg, gates);
    convert_bf16<<<cgrid, blk, 0, stream>>>(x, xb);

    // Phase 5: MoE experts
    const int nmoe = T_ * D_;
    zero_kernel<<<dim3((nmoe + 255) / 256), blk, 0, stream>>>(moe, nmoe);
    for (int e = 0; e < E_; ++e) {
        transpose_to_bf16<<<dim3(F_/64, D_/64), blk, 0, stream>>>(
            W1 + (size_t)e * D_ * F_, w1t, D_, F_);
        transpose_to_bf16<<<dim3(D_/64, F_/64), blk, 0, stream>>>(
            W2 + (size_t)e * F_ * D_, w2t, F_, D_);
        gemm_bt<1><<<gF, blk, 0, stream>>>(xb, w1t, b1 + (size_t)e * F_,
                                           nullptr, hb, T_, F_, D_, nullptr, 0);
        gemm_bt<2><<<gD, blk, 0, stream>>>(hb, w2t, b2 + (size_t)e * D_,
                                           moe, nullptr, T_, D_, F_, gates, e);
    }

    // Phase 6: residual + LN2 -> output
    ln_kernel<<<dim3(T_), blk, 0, stream>>>(x, moe, ln2g, ln2b, out);
}